// Round 7
// baseline (525.822 us; speedup 1.0000x reference)
//
#include <hip/hip_runtime.h>
#include <stdint.h>
#include <stddef.h>

#define NN 8192      // nodes
#define KD 256       // in_dim
#define CD 256       // out_dim*heads
#define FD 128       // out_dim
#define BI 64        // i-rows per k_gat block (8 waves, 512 threads)
#define PACK_BLOCKS 512

typedef __attribute__((ext_vector_type(4))) float f32x4;
typedef __attribute__((ext_vector_type(8))) short b16x8;

__device__ __forceinline__ unsigned short f2bf(float x) {
    unsigned int u = __float_as_uint(x);
    u += 0x7fffu + ((u >> 16) & 1u);
    return (unsigned short)(u >> 16);
}

// w_j = adj ? max(Ei*Fj, Gi*Hj) : 0  (== exp(leaky_relu(s_i+d_j)), masked)
// for 8 j's; bf16 A-fragment into regs; returns sum of w.
__device__ __forceinline__ float wsel_frag(
    int m8, const float4 f0, const float4 f1, const float4 h0, const float4 h1,
    float Ei, float Gi, b16x8* out)
{
    const float ff[8] = {f0.x, f0.y, f0.z, f0.w, f1.x, f1.y, f1.z, f1.w};
    const float hh[8] = {h0.x, h0.y, h0.z, h0.w, h1.x, h1.y, h1.z, h1.w};
    float e[8]; float dp = 0.f;
#pragma unroll
    for (int k = 0; k < 8; ++k) {
        float w = fmaxf(Ei * ff[k], Gi * hh[k]);
        w = (m8 & (1 << k)) ? w : 0.f;
        dp += w; e[k] = w;
    }
    union { unsigned short us[8]; b16x8 v; } pk;
#if __has_builtin(__builtin_amdgcn_cvt_pk_bf16_f32)
#pragma unroll
    for (int k = 0; k < 4; ++k) {
        auto p = __builtin_amdgcn_cvt_pk_bf16_f32(e[2 * k], e[2 * k + 1]);
        __builtin_memcpy(&pk.us[2 * k], &p, 4);
    }
#else
#pragma unroll
    for (int k = 0; k < 8; ++k) pk.us[k] = f2bf(e[k]);
#endif
    *out = pk.v;
    return dp;
}

// ---------------------------------------------------------------------------
// Kernel 1 (fused front):
//  blocks [0,128): T = feat @ W.T (bf16 MFMA) + E/G/F/H score-exponentials +
//                  tiled bf16 TB[j>>5][c][j&31]
//  blocks [128,128+PACK_BLOCKS): adj -> tiled bitmask MT[i>>5][jb][i&31]
// ---------------------------------------------------------------------------
__global__ __launch_bounds__(256) void k_front(
    const float* __restrict__ feat, const float* __restrict__ W,
    const float* __restrict__ asrc, const float* __restrict__ adst,
    const int* __restrict__ adj, unsigned char* __restrict__ MT,
    unsigned short* __restrict__ TB,
    float* __restrict__ SE, float* __restrict__ SG,
    float* __restrict__ SF, float* __restrict__ SH)
{
    __shared__ unsigned short a_lds[64 * 32];    // 4KB
    __shared__ unsigned short b_lds[256 * 32];   // 16KB
    __shared__ unsigned short tr_lds[256 * 72];  // 36KB
    __shared__ float sc_lds[4][64];              // 1KB
    __shared__ float dc_lds[4][64];              // 1KB
    __shared__ unsigned char pk_lds[1024 * 16];  // 16KB (pack path)

    const int t = threadIdx.x;

    if (blockIdx.x >= 128) {
        // ---- pack path: 16 rows of adj -> MT[I][jb][r32], streaming ----
        const int pb = blockIdx.x - 128;
        const int I = pb >> 1, half = pb & 1;
        const int row_base = I * 32 + half * 16;
        const int4* a4 = (const int4*)adj;   // NN/4 = 2048 int4 per row
#pragma unroll 4
        for (int st = 0; st < 128; ++st) {
            const int g = st * 256 + t;          // 0..32767
            const int row16 = g >> 11;           // wave-uniform
            const int j4 = g & 2047;
            const int4 v = a4[(size_t)(row_base + row16) * 2048 + j4];
            unsigned int nib = (v.x != 0 ? 1u : 0u) | (v.y != 0 ? 2u : 0u) |
                               (v.z != 0 ? 4u : 0u) | (v.w != 0 ? 8u : 0u);
            unsigned int b = nib << (4 * (t & 1));
            b |= __shfl_xor(b, 1);
            if ((t & 1) == 0) pk_lds[(j4 >> 1) * 16 + row16] = (unsigned char)b;
        }
        __syncthreads();
        unsigned int* mt32 = (unsigned int*)MT;
        const unsigned int* src = (const unsigned int*)pk_lds;
        for (int i = 0; i < 16; ++i) {
            const int w = i * 256 + t;           // 4096 words
            const int jb = w >> 2, r4 = w & 3;
            mt32[(size_t)I * 8192 + jb * 8 + half * 4 + r4] = src[w];
        }
        return;
    }

    // ---- transform path ----
    const int wave = t >> 6, lane = t & 63;
    const int l15 = lane & 15, quad = lane >> 4;
    const int n0 = blockIdx.x * 64;
    const int ai = t >> 2, ag = t & 3;

    f32x4 acc[4][4] = {};
    for (int kc = 0; kc < 8; ++kc) {
        const int k0 = kc * 32;
        __syncthreads();
        { // stage A: features[n0+ai][k0 + ag*8 .. +7] -> bf16
            const float* src = feat + (size_t)(n0 + ai) * KD + k0 + ag * 8;
            const float4 v0 = *(const float4*)src;
            const float4 v1 = *(const float4*)(src + 4);
            union { unsigned short us[8]; b16x8 v; } pk;
            pk.us[0] = f2bf(v0.x); pk.us[1] = f2bf(v0.y);
            pk.us[2] = f2bf(v0.z); pk.us[3] = f2bf(v0.w);
            pk.us[4] = f2bf(v1.x); pk.us[5] = f2bf(v1.y);
            pk.us[6] = f2bf(v1.z); pk.us[7] = f2bf(v1.w);
            const int slot = ag ^ ((ai >> 1) & 3);
            *(b16x8*)&a_lds[ai * 32 + slot * 8] = pk.v;
        }
        for (int p = 0; p < 4; ++p) { // stage B: W[c][k0 + g*8 .. +7]
            const int G = p * 256 + t;
            const int c = G >> 2, g = G & 3;
            const float* src = W + (size_t)c * KD + k0 + g * 8;
            const float4 v0 = *(const float4*)src;
            const float4 v1 = *(const float4*)(src + 4);
            union { unsigned short us[8]; b16x8 v; } pk;
            pk.us[0] = f2bf(v0.x); pk.us[1] = f2bf(v0.y);
            pk.us[2] = f2bf(v0.z); pk.us[3] = f2bf(v0.w);
            pk.us[4] = f2bf(v1.x); pk.us[5] = f2bf(v1.y);
            pk.us[6] = f2bf(v1.z); pk.us[7] = f2bf(v1.w);
            const int slot = g ^ ((c >> 1) & 3);
            *(b16x8*)&b_lds[c * 32 + slot * 8] = pk.v;
        }
        __syncthreads();
        b16x8 af[4], bfr[4];
        for (int mt = 0; mt < 4; ++mt) {
            const int m = mt * 16 + l15;
            af[mt] = *(const b16x8*)&a_lds[m * 32 + (quad ^ ((m >> 1) & 3)) * 8];
        }
        for (int nt = 0; nt < 4; ++nt) {
            const int c = wave * 64 + nt * 16 + l15;
            bfr[nt] = *(const b16x8*)&b_lds[c * 32 + (quad ^ ((c >> 1) & 3)) * 8];
        }
        for (int mt = 0; mt < 4; ++mt)
            for (int nt = 0; nt < 4; ++nt)
                acc[mt][nt] = __builtin_amdgcn_mfma_f32_16x16x32_bf16(
                    af[mt], bfr[nt], acc[mt][nt], 0, 0, 0);
    }

    // ---- epilogue: score-exponentials + tiled bf16 store ----
    float aS[4], aD[4];
    for (int nt = 0; nt < 4; ++nt) {
        const int c = wave * 64 + nt * 16 + l15;
        aS[nt] = asrc[c]; aD[nt] = adst[c];
    }
    for (int mt = 0; mt < 4; ++mt)
        for (int r = 0; r < 4; ++r) {
            float vs = 0.f, vd = 0.f;
            for (int nt = 0; nt < 4; ++nt) {
                const float x = acc[mt][nt][r];
                vs += x * aS[nt]; vd += x * aD[nt];
            }
            vs += __shfl_xor(vs, 1); vd += __shfl_xor(vd, 1);
            vs += __shfl_xor(vs, 2); vd += __shfl_xor(vd, 2);
            vs += __shfl_xor(vs, 4); vd += __shfl_xor(vd, 4);
            vs += __shfl_xor(vs, 8); vd += __shfl_xor(vd, 8);
            if (l15 == 0) {
                const int nl = mt * 16 + quad * 4 + r;
                sc_lds[wave][nl] = vs; dc_lds[wave][nl] = vd;
            }
        }
    for (int mt = 0; mt < 4; ++mt)
        for (int nt = 0; nt < 4; ++nt)
            for (int r = 0; r < 4; ++r) {
                const int c = wave * 64 + nt * 16 + l15;
                const int n = mt * 16 + quad * 4 + r;
                tr_lds[c * 72 + n] = f2bf(acc[mt][nt][r]);
            }
    __syncthreads();
    if (t < 128) {
        const int n = t >> 1, h = t & 1;
        const float s = sc_lds[h * 2][n] + sc_lds[h * 2 + 1][n];
        const float d = dc_lds[h * 2][n] + dc_lds[h * 2 + 1][n];
        SE[(size_t)h * NN + n0 + n] = __expf(s);
        SG[(size_t)h * NN + n0 + n] = __expf(0.2f * s);
        SF[(size_t)h * NN + n0 + n] = __expf(d);
        SH[(size_t)h * NN + n0 + n] = __expf(0.2f * d);
    }
    for (int p = 0; p < 8; ++p) {
        const int idx = p * 256 + t;       // 2048 granules
        const int c = idx >> 3, g = idx & 7;
        unsigned short* dst = TB + ((size_t)((n0 >> 5) + (g >> 2))) * 8192
                              + c * 32 + (g & 3) * 8;
        *(b16x8*)dst = *(const b16x8*)&tr_lds[c * 72 + g * 8];
    }
}

// ---------------------------------------------------------------------------
// Kernel 2: fused masked-softmax aggregation — BARRIER-FREE, LDS-FREE.
// Tiled TB -> every B-frag load is a 1KB-coalesced dwordx4 (L2-resident).
// A-frags in registers from tiled-MT mask bytes + F/H broadcasts.
// Register double-buffer, manual 2x unroll. grid=(128, jsplit), block=512.
// ---------------------------------------------------------------------------
__global__ __launch_bounds__(512, 4) void k_gat(
    const unsigned char* __restrict__ MT, const unsigned short* __restrict__ TB,
    const float* __restrict__ SE, const float* __restrict__ SG,
    const float* __restrict__ SF, const float* __restrict__ SH,
    float* __restrict__ num_part,   // [jsplit][NN][CD]
    float* __restrict__ den_part,   // [jsplit][2][NN]
    int njt)
{
    const int t = threadIdx.x;
    const int wave = t >> 6, lane = t & 63;
    const int l15 = lane & 15, quad = lane >> 4;
    const int fh = wave & 1, mh = (wave >> 1) & 1, ih = wave >> 2;
    const int i0 = blockIdx.x * BI + ih * 32;   // this wave's 32-row subtile
    const int chunk = blockIdx.y;
    const size_t jbase = (size_t)chunk * njt * 32;
    const int cb = mh * 128 + fh * 64;

    // E/G for this wave's two row-tiles (head mh)
    const float Ei0 = SE[(size_t)mh * NN + i0 + l15];
    const float Ei1 = SE[(size_t)mh * NN + i0 + 16 + l15];
    const float Gi0 = SG[(size_t)mh * NN + i0 + l15];
    const float Gi1 = SG[(size_t)mh * NN + i0 + 16 + l15];

    // tiled pointers (per-lane)
    const unsigned short* tbL = TB + (jbase >> 5) * 8192 + (size_t)(cb + l15) * 32 + quad * 8;
    const unsigned char*  mL  = MT + ((size_t)(i0 >> 5)) * 32768 + (jbase >> 3) * 32
                                 + quad * 32 + l15;
    const float* fp = SF + (size_t)mh * NN + jbase + quad * 8;
    const float* hp = SH + (size_t)mh * NN + jbase + quad * 8;

    f32x4 acc[2][4] = {};
    float den0 = 0.f, den1 = 0.f;

    // register sets A/B (double buffer)
    int   mA0, mA1, mB0, mB1;
    float4 fA0, fA1, hA0, hA1, fB0, fB1, hB0, hB1;
    b16x8 bA[4], bB[4];

    // prologue: load iter 0 into set A
    mA0 = mL[0]; mA1 = mL[16];
    fA0 = *(const float4*)(fp);     fA1 = *(const float4*)(fp + 4);
    hA0 = *(const float4*)(hp);     hA1 = *(const float4*)(hp + 4);
#pragma unroll
    for (int nt = 0; nt < 4; ++nt) bA[nt] = *(const b16x8*)(tbL + nt * 512);

    for (int jt = 0; jt < njt; jt += 2) {
        // ---- body A: prefetch jt+1 -> set B; compute jt from set A ----
        {
            const int jn = jt + 1;   // always < njt (njt even)
            mB0 = mL[jn * 128]; mB1 = mL[jn * 128 + 16];
            fB0 = *(const float4*)(fp + jn * 32); fB1 = *(const float4*)(fp + jn * 32 + 4);
            hB0 = *(const float4*)(hp + jn * 32); hB1 = *(const float4*)(hp + jn * 32 + 4);
#pragma unroll
            for (int nt = 0; nt < 4; ++nt)
                bB[nt] = *(const b16x8*)(tbL + (size_t)jn * 8192 + nt * 512);
            b16x8 a0, a1;
            den0 += wsel_frag(mA0, fA0, fA1, hA0, hA1, Ei0, Gi0, &a0);
            den1 += wsel_frag(mA1, fA0, fA1, hA0, hA1, Ei1, Gi1, &a1);
#pragma unroll
            for (int nt = 0; nt < 4; ++nt)
                acc[0][nt] = __builtin_amdgcn_mfma_f32_16x16x32_bf16(
                    a0, bA[nt], acc[0][nt], 0, 0, 0);
#pragma unroll
            for (int nt = 0; nt < 4; ++nt)
                acc[1][nt] = __builtin_amdgcn_mfma_f32_16x16x32_bf16(
                    a1, bA[nt], acc[1][nt], 0, 0, 0);
        }
        // ---- body B: prefetch jt+2 -> set A (clamped); compute jt+1 from B ----
        {
            const int jn = (jt + 2 < njt) ? jt + 2 : njt - 1;  // tail load unused
            mA0 = mL[jn * 128]; mA1 = mL[jn * 128 + 16];
            fA0 = *(const float4*)(fp + jn * 32); fA1 = *(const float4*)(fp + jn * 32 + 4);
            hA0 = *(const float4*)(hp + jn * 32); hA1 = *(const float4*)(hp + jn * 32 + 4);
#pragma unroll
            for (int nt = 0; nt < 4; ++nt)
                bA[nt] = *(const b16x8*)(tbL + (size_t)jn * 8192 + nt * 512);
            b16x8 a0, a1;
            den0 += wsel_frag(mB0, fB0, fB1, hB0, hB1, Ei0, Gi0, &a0);
            den1 += wsel_frag(mB1, fB0, fB1, hB0, hB1, Ei1, Gi1, &a1);
#pragma unroll
            for (int nt = 0; nt < 4; ++nt)
                acc[0][nt] = __builtin_amdgcn_mfma_f32_16x16x32_bf16(
                    a0, bB[nt], acc[0][nt], 0, 0, 0);
#pragma unroll
            for (int nt = 0; nt < 4; ++nt)
                acc[1][nt] = __builtin_amdgcn_mfma_f32_16x16x32_bf16(
                    a1, bB[nt], acc[1][nt], 0, 0, 0);
        }
    }

    // den: reduce over the 4 quads; fh==0 wave writes (fh==1 is a duplicate)
    den0 += __shfl_xor(den0, 16); den0 += __shfl_xor(den0, 32);
    den1 += __shfl_xor(den1, 16); den1 += __shfl_xor(den1, 32);
    if (fh == 0 && quad == 0) {
        den_part[((size_t)chunk * 2 + mh) * NN + i0 + l15] = den0;
        den_part[((size_t)chunk * 2 + mh) * NN + i0 + 16 + l15] = den1;
    }

    float* np_ = num_part + (size_t)chunk * NN * CD;
#pragma unroll
    for (int mt = 0; mt < 2; ++mt)
#pragma unroll
        for (int nt = 0; nt < 4; ++nt)
#pragma unroll
            for (int r = 0; r < 4; ++r) {
                const int n = i0 + mt * 16 + quad * 4 + r;
                const int c = cb + nt * 16 + l15;
                np_[(size_t)n * CD + c] = acc[mt][nt][r];
            }
}

// ---------------------------------------------------------------------------
// Kernel 3: combine partials, normalize, mean over heads.  grid=4096
// ---------------------------------------------------------------------------
__global__ __launch_bounds__(256) void k_combine(
    const float* __restrict__ num_part, const float* __restrict__ den_part,
    float* __restrict__ out, int jsplit)
{
    const int idx = blockIdx.x * 256 + threadIdx.x;   // NN*FD
    const int n = idx >> 7, f = idx & 127;
    const size_t row = (size_t)n * CD;
    float n0 = 0.f, n1 = 0.f, d0 = 0.f, d1 = 0.f;
    for (int c = 0; c < jsplit; ++c) {
        const size_t base = (size_t)c * NN * CD;
        n0 += num_part[base + row + f];
        n1 += num_part[base + row + 128 + f];
        d0 += den_part[((size_t)c * 2 + 0) * NN + n];
        d1 += den_part[((size_t)c * 2 + 1) * NN + n];
    }
    const float r0 = d0 != 0.f ? n0 / d0 : 0.f;
    const float r1 = d1 != 0.f ? n1 / d1 : 0.f;
    out[idx] = 0.5f * (r0 + r1);
}

// ---------------------------------------------------------------------------
extern "C" void kernel_launch(void* const* d_in, const int* in_sizes, int n_in,
                              void* d_out, int out_size, void* d_ws, size_t ws_size,
                              hipStream_t stream) {
    const float* feat = (const float*)d_in[0];
    const int*   adj  = (const int*)d_in[1];
    const float* W    = (const float*)d_in[2];
    const float* asrc = (const float*)d_in[3];
    const float* adst = (const float*)d_in[4];
    float* out = (float*)d_out;

    const int jsplit = (ws_size >= ((size_t)45 << 20)) ? 4 : 2;
    const int njt = (NN / jsplit) / 32;

    char* ws = (char*)d_ws;
    unsigned short* TB = (unsigned short*)ws;                        // 4 MB tiled T
    float* SE = (float*)(ws + ((size_t)4 << 20));                    // 64 KB
    float* SG = (float*)(ws + ((size_t)4 << 20) + (64 << 10));       // 64 KB
    float* SF = (float*)(ws + ((size_t)4 << 20) + (128 << 10));      // 64 KB
    float* SH = (float*)(ws + ((size_t)4 << 20) + (192 << 10));      // 64 KB
    float* den = (float*)(ws + ((size_t)4 << 20) + (256 << 10));     // <=256 KB
    unsigned char* MT = (unsigned char*)(ws + ((size_t)5 << 20));    // 8 MB tiled mask
    float* nump = (float*)(ws + ((size_t)13 << 20));                 // jsplit*8 MB

    k_front<<<128 + PACK_BLOCKS, 256, 0, stream>>>(feat, W, asrc, adst, adj,
                                                   MT, TB, SE, SG, SF, SH);
    k_gat<<<dim3(NN / BI, jsplit), 512, 0, stream>>>(MT, TB, SE, SG, SF, SH,
                                                     nump, den, njt);
    k_combine<<<NN * FD / 256, 256, 0, stream>>>(nump, den, out, jsplit);
}